// Round 1
// baseline (4317.339 us; speedup 1.0000x reference)
//
#include <hip/hip_runtime.h>

// GCN 2-layer fused pipeline.
// Identity used: Agg(X @ W) == Agg(X) @ W  (aggregation is linear, per-node).
// Layer 1: aggregate x (width 128) -> GEMM(+b1, relu).
// Layer 2: GEMM (width 64) -> aggregate -> +b2 (+self term) fused in init pass.

constexpr int NN = 100000;   // nodes
constexpr int NE = 1600000;  // edges

// ---------------- degree histogram ----------------
__global__ __launch_bounds__(256) void k_deg(const int* __restrict__ cols,
                                             int* __restrict__ deg) {
  int e = blockIdx.x * 256 + threadIdx.x;
  if (e < NE) atomicAdd(&deg[cols[e]], 1);
}

// dinv[i] = rsqrt(deg[i]+1)  (self-loop adds 1); AggX[i] = x[i]*dinv^2 (self-loop term)
__global__ __launch_bounds__(256) void k_init_agg(const float4* __restrict__ x4,
                                                  const int* __restrict__ deg,
                                                  float* __restrict__ dinv,
                                                  float4* __restrict__ agg4) {
  int gid = blockIdx.x * 256 + threadIdx.x;  // over NN*32 float4 units
  if (gid >= NN * 32) return;
  int node = gid >> 5;
  float d = rsqrtf((float)deg[node] + 1.0f);
  if ((gid & 31) == 0) dinv[node] = d;
  float s = d * d;
  float4 v = x4[gid];
  agg4[gid] = make_float4(v.x * s, v.y * s, v.z * s, v.w * s);
}

// edge scatter, width 128: 32 threads/edge, float4 each, 4 atomicAdds
__global__ __launch_bounds__(256) void k_agg1(const float4* __restrict__ x4,
                                              const int* __restrict__ rows,
                                              const int* __restrict__ cols,
                                              const float* __restrict__ dinv,
                                              float* __restrict__ agg) {
  int gid = blockIdx.x * 256 + threadIdx.x;  // over NE*32
  if (gid >= NE * 32) return;
  int e = gid >> 5, q = gid & 31;
  int r = rows[e], c = cols[e];
  float nrm = dinv[r] * dinv[c];
  float4 v = x4[(size_t)r * 32 + q];
  float* dst = agg + (size_t)c * 128 + q * 4;
  atomicAdd(dst + 0, v.x * nrm);
  atomicAdd(dst + 1, v.y * nrm);
  atomicAdd(dst + 2, v.z * nrm);
  atomicAdd(dst + 3, v.w * nrm);
}

// edge scatter, width 64: 16 threads/edge
__global__ __launch_bounds__(256) void k_agg2(const float4* __restrict__ h4,
                                              const int* __restrict__ rows,
                                              const int* __restrict__ cols,
                                              const float* __restrict__ dinv,
                                              float* __restrict__ out) {
  int gid = blockIdx.x * 256 + threadIdx.x;  // over NE*16
  if (gid >= NE * 16) return;
  int e = gid >> 4, q = gid & 15;
  int r = rows[e], c = cols[e];
  float nrm = dinv[r] * dinv[c];
  float4 v = h4[(size_t)r * 16 + q];
  float* dst = out + (size_t)c * 64 + q * 4;
  atomicAdd(dst + 0, v.x * nrm);
  atomicAdd(dst + 1, v.y * nrm);
  atomicAdd(dst + 2, v.z * nrm);
  atomicAdd(dst + 3, v.w * nrm);
}

// out[i] = h2[i]*dinv[i]^2 + b2   (self-loop term + bias; full overwrite of d_out)
__global__ __launch_bounds__(256) void k_init_out(const float4* __restrict__ h4,
                                                  const float* __restrict__ dinv,
                                                  const float* __restrict__ b2,
                                                  float4* __restrict__ out4) {
  int gid = blockIdx.x * 256 + threadIdx.x;  // over NN*16
  if (gid >= NN * 16) return;
  int node = gid >> 4;
  int q = gid & 15;
  float d = dinv[node];
  float s = d * d;
  float4 v = h4[gid];
  float4 bv = reinterpret_cast<const float4*>(b2)[q];
  out4[gid] = make_float4(v.x * s + bv.x, v.y * s + bv.y, v.z * s + bv.z, v.w * s + bv.w);
}

// ---------------- GEMM: C[M,BN] = A[M,128] @ W[128,BN] (+bias, relu) ----------------
// Block tile 128 rows x BN cols, 256 threads (16 tx x 16 ty), thread tile 8 x (BN/16).
// x staged transposed in LDS (xs[k][row]) so compute reads are lane-broadcast +
// conflict-free b128; W staged flat.
template <int BN, bool BIASRELU>
__global__ __launch_bounds__(256) void k_gemm(const float* __restrict__ A,
                                              const float* __restrict__ W,
                                              const float* __restrict__ bias,
                                              float* __restrict__ C, int M) {
  constexpr int TN = BN / 16;  // 8 or 4
  __shared__ __align__(16) float xs[32][132];
  __shared__ __align__(16) float ws[32][BN];
  const int tid = threadIdx.x;
  const int tx = tid & 15, ty = tid >> 4;
  const int ry = ty * 8, cx = tx * TN;
  const int rowBase = blockIdx.x * 128;

  float acc[8][TN];
#pragma unroll
  for (int i = 0; i < 8; i++)
#pragma unroll
    for (int j = 0; j < TN; j++) acc[i][j] = 0.0f;

  for (int kc = 0; kc < 128; kc += 32) {
    // stage W rows kc..kc+31 (contiguous)
#pragma unroll
    for (int i = tid; i < 32 * BN / 4; i += 256) {
      reinterpret_cast<float4*>(&ws[0][0])[i] =
          reinterpret_cast<const float4*>(W + (size_t)kc * BN)[i];
    }
    // stage x chunk transposed: xs[k][r]
#pragma unroll
    for (int i = tid; i < 1024; i += 256) {
      int r = i >> 3, j = i & 7;
      int row = rowBase + r;
      float4 v = make_float4(0.f, 0.f, 0.f, 0.f);
      if (row < M)
        v = *reinterpret_cast<const float4*>(A + (size_t)row * 128 + kc + 4 * j);
      xs[4 * j + 0][r] = v.x;
      xs[4 * j + 1][r] = v.y;
      xs[4 * j + 2][r] = v.z;
      xs[4 * j + 3][r] = v.w;
    }
    __syncthreads();
#pragma unroll
    for (int k = 0; k < 32; k++) {
      float4 xa = *reinterpret_cast<const float4*>(&xs[k][ry]);
      float4 xb = *reinterpret_cast<const float4*>(&xs[k][ry + 4]);
      float xv[8] = {xa.x, xa.y, xa.z, xa.w, xb.x, xb.y, xb.z, xb.w};
      float wv[TN];
      float4 wa = *reinterpret_cast<const float4*>(&ws[k][cx]);
      wv[0] = wa.x; wv[1] = wa.y; wv[2] = wa.z; wv[3] = wa.w;
      if constexpr (TN == 8) {
        float4 wb = *reinterpret_cast<const float4*>(&ws[k][cx + 4]);
        wv[4] = wb.x; wv[5] = wb.y; wv[6] = wb.z; wv[7] = wb.w;
      }
#pragma unroll
      for (int i = 0; i < 8; i++)
#pragma unroll
        for (int j = 0; j < TN; j++) acc[i][j] += xv[i] * wv[j];
    }
    __syncthreads();
  }

#pragma unroll
  for (int i = 0; i < 8; i++) {
    int row = rowBase + ry + i;
    if (row < M) {
      float* cp = C + (size_t)row * BN + cx;
#pragma unroll
      for (int j0 = 0; j0 < TN; j0 += 4) {
        float4 o = make_float4(acc[i][j0 + 0], acc[i][j0 + 1], acc[i][j0 + 2],
                               acc[i][j0 + 3]);
        if constexpr (BIASRELU) {
          float4 bv = *reinterpret_cast<const float4*>(&bias[cx + j0]);
          o.x = fmaxf(o.x + bv.x, 0.f);
          o.y = fmaxf(o.y + bv.y, 0.f);
          o.z = fmaxf(o.z + bv.z, 0.f);
          o.w = fmaxf(o.w + bv.w, 0.f);
        }
        *reinterpret_cast<float4*>(cp + j0) = o;
      }
    }
  }
}

extern "C" void kernel_launch(void* const* d_in, const int* in_sizes, int n_in,
                              void* d_out, int out_size, void* d_ws, size_t ws_size,
                              hipStream_t stream) {
  const float* x  = (const float*)d_in[0];
  const int*   ei = (const int*)d_in[1];  // [2, NE] row-major
  const int* rows = ei;
  const int* cols = ei + NE;
  // d_in[2] edge_weight: forward overwrites with ones -> unused
  const float* W1 = (const float*)d_in[3];
  const float* b1 = (const float*)d_in[4];
  const float* W2 = (const float*)d_in[5];
  const float* b2 = (const float*)d_in[6];
  float* out = (float*)d_out;

  // workspace carve (needs ~104.5 MB)
  char* base = (char*)d_ws;
  int*   deg  = (int*)(base);                     // 400 KB
  float* dinv = (float*)(base + (1 << 20));       // 400 KB
  float* aggx = (float*)(base + (2 << 20));       // 51.2 MB (AggX; later reused as h2)
  float* h1   = (float*)(base + (2 << 20) + (size_t)NN * 128 * 4);  // 51.2 MB
  float* h2   = aggx;  // 25.6 MB, AggX dead after gemm1

  hipMemsetAsync(deg, 0, NN * sizeof(int), stream);
  k_deg<<<(NE + 255) / 256, 256, 0, stream>>>(cols, deg);
  k_init_agg<<<(NN * 32) / 256, 256, 0, stream>>>((const float4*)x, deg, dinv,
                                                  (float4*)aggx);
  k_agg1<<<(NE * 32) / 256, 256, 0, stream>>>((const float4*)x, rows, cols, dinv, aggx);
  k_gemm<128, true><<<(NN + 127) / 128, 256, 0, stream>>>(aggx, W1, b1, h1, NN);
  k_gemm<64, false><<<(NN + 127) / 128, 256, 0, stream>>>(h1, W2, nullptr, h2, NN);
  k_init_out<<<(NN * 16) / 256, 256, 0, stream>>>((const float4*)h2, dinv, b2,
                                                  (float4*)out);
  k_agg2<<<(NE * 16) / 256, 256, 0, stream>>>((const float4*)h2, rows, cols, dinv, out);
}

// Round 2
// 643.353 us; speedup vs baseline: 6.7107x; 6.7107x over previous
//
#include <hip/hip_runtime.h>

// GCN 2-layer, CSR-gather formulation (no float atomics).
// Agg(X@W) == Agg(X)@W. norm = dinv[r]*dinv[c] factored:
//   y = x * dinv                    (elementwise)
//   aggX[c] = dinv[c] * (y[c] + sum_{r in in(c)} y[r])      (self-loop = y[c])
//   h1 = relu(aggX @ W1 + b1)
//   z  = (h1 @ W2) * dinv           (dinv folded into GEMM epilogue)
//   out[c] = dinv[c] * (z[c] + sum z[r]) + b2

constexpr int NN = 100000;   // nodes
constexpr int NE = 1600000;  // edges

// ---------------- degree histogram (int atomics, L2-resident) ----------------
__global__ __launch_bounds__(256) void k_deg(const int* __restrict__ cols,
                                             int* __restrict__ deg) {
  int e = blockIdx.x * 256 + threadIdx.x;
  if (e < NE) atomicAdd(&deg[cols[e]], 1);
}

// ---------------- exclusive scan of deg -> rowptr (3 kernels) ----------------
// A: per-block (1024 elems) local exclusive scan + block sums
__global__ __launch_bounds__(256) void k_scanA(const int* __restrict__ deg,
                                               int* __restrict__ rowptr,
                                               int* __restrict__ blockSum) {
  __shared__ int s[256];
  int t = threadIdx.x, b = blockIdx.x;
  int base = b * 1024 + t * 4;
  int d0 = (base + 0 < NN) ? deg[base + 0] : 0;
  int d1 = (base + 1 < NN) ? deg[base + 1] : 0;
  int d2 = (base + 2 < NN) ? deg[base + 2] : 0;
  int d3 = (base + 3 < NN) ? deg[base + 3] : 0;
  int tsum = d0 + d1 + d2 + d3;
  s[t] = tsum;
  __syncthreads();
  for (int off = 1; off < 256; off <<= 1) {
    int tmp = (t >= off) ? s[t - off] : 0;
    __syncthreads();
    s[t] += tmp;
    __syncthreads();
  }
  int ex = s[t] - tsum;  // exclusive within block
  if (base + 0 < NN) rowptr[base + 0] = ex;
  if (base + 1 < NN) rowptr[base + 1] = ex + d0;
  if (base + 2 < NN) rowptr[base + 2] = ex + d0 + d1;
  if (base + 3 < NN) rowptr[base + 3] = ex + d0 + d1 + d2;
  if (t == 255) blockSum[b] = ex + tsum;
}

// B: single block scans the (<=128) block sums
__global__ __launch_bounds__(128) void k_scanB(int* __restrict__ blockSum,
                                               int* __restrict__ blockOff,
                                               int nblocks) {
  __shared__ int s[128];
  int t = threadIdx.x;
  int v = (t < nblocks) ? blockSum[t] : 0;
  s[t] = v;
  __syncthreads();
  for (int off = 1; off < 128; off <<= 1) {
    int tmp = (t >= off) ? s[t - off] : 0;
    __syncthreads();
    s[t] += tmp;
    __syncthreads();
  }
  if (t < nblocks) blockOff[t] = s[t] - v;
}

// C: add block offsets; also compute dinv = rsqrt(deg+1)
__global__ __launch_bounds__(256) void k_scanC(int* __restrict__ rowptr,
                                               const int* __restrict__ blockOff,
                                               const int* __restrict__ deg,
                                               float* __restrict__ dinv) {
  int i = blockIdx.x * 256 + threadIdx.x;
  if (i < NN) {
    rowptr[i] += blockOff[i >> 10];
    dinv[i] = rsqrtf((float)deg[i] + 1.0f);
  }
}

// ---------------- CSR fill: rowptr becomes END pointers ----------------
__global__ __launch_bounds__(256) void k_fill(const int* __restrict__ rows,
                                              const int* __restrict__ cols,
                                              int* __restrict__ rowptr,
                                              int* __restrict__ srcIdx) {
  int e = blockIdx.x * 256 + threadIdx.x;
  if (e < NE) {
    int c = cols[e];
    int pos = atomicAdd(&rowptr[c], 1);
    srcIdx[pos] = rows[e];
  }
}

// ---------------- y = x * dinv (elementwise) ----------------
__global__ __launch_bounds__(256) void k_y(const float4* __restrict__ x4,
                                           const float* __restrict__ dinv,
                                           float4* __restrict__ y4) {
  int gid = blockIdx.x * 256 + threadIdx.x;  // NN*32
  if (gid >= NN * 32) return;
  float s = dinv[gid >> 5];
  float4 v = x4[gid];
  y4[gid] = make_float4(v.x * s, v.y * s, v.z * s, v.w * s);
}

// ---------------- gather-aggregate, width 128 (float2/lane, wave per node) ----
__global__ __launch_bounds__(256) void k_gath1(const float2* __restrict__ y2,
                                               const int* __restrict__ rowptr_end,
                                               const int* __restrict__ deg,
                                               const int* __restrict__ srcIdx,
                                               const float* __restrict__ dinv,
                                               float2* __restrict__ agg) {
  int node = blockIdx.x * 4 + (threadIdx.x >> 6);
  int lane = threadIdx.x & 63;
  if (node >= NN) return;
  int d = deg[node];
  int p = rowptr_end[node] - d;  // start
  float2 acc = y2[(size_t)node * 64 + lane];  // self-loop term
  int src_next = (d > 0) ? srcIdx[p] : 0;
  for (int k = 0; k < d; k++) {
    int src = src_next;
    if (k + 1 < d) src_next = srcIdx[p + k + 1];
    float2 v = y2[(size_t)src * 64 + lane];
    acc.x += v.x;
    acc.y += v.y;
  }
  float s = dinv[node];
  agg[(size_t)node * 64 + lane] = make_float2(acc.x * s, acc.y * s);
}

// ---------------- gather-aggregate, width 64 (+b2 epilogue) -------------------
__global__ __launch_bounds__(256) void k_gath2(const float* __restrict__ z,
                                               const int* __restrict__ rowptr_end,
                                               const int* __restrict__ deg,
                                               const int* __restrict__ srcIdx,
                                               const float* __restrict__ dinv,
                                               const float* __restrict__ b2,
                                               float* __restrict__ out) {
  int node = blockIdx.x * 4 + (threadIdx.x >> 6);
  int lane = threadIdx.x & 63;
  if (node >= NN) return;
  int d = deg[node];
  int p = rowptr_end[node] - d;
  float acc = z[(size_t)node * 64 + lane];
  int src_next = (d > 0) ? srcIdx[p] : 0;
  for (int k = 0; k < d; k++) {
    int src = src_next;
    if (k + 1 < d) src_next = srcIdx[p + k + 1];
    acc += z[(size_t)src * 64 + lane];
  }
  out[(size_t)node * 64 + lane] = acc * dinv[node] + b2[lane];
}

// ---------------- GEMM: C[M,BN] = A[M,128] @ W[128,BN] (+bias/relu | *rowscale) ----
template <int BN, bool BIASRELU, bool ROWSCALE>
__global__ __launch_bounds__(256) void k_gemm(const float* __restrict__ A,
                                              const float* __restrict__ W,
                                              const float* __restrict__ bias,
                                              const float* __restrict__ rowscale,
                                              float* __restrict__ C, int M) {
  constexpr int TN = BN / 16;  // 8 or 4
  __shared__ __align__(16) float xs[32][132];
  __shared__ __align__(16) float ws[32][BN];
  const int tid = threadIdx.x;
  const int tx = tid & 15, ty = tid >> 4;
  const int ry = ty * 8, cx = tx * TN;
  const int rowBase = blockIdx.x * 128;

  float acc[8][TN];
#pragma unroll
  for (int i = 0; i < 8; i++)
#pragma unroll
    for (int j = 0; j < TN; j++) acc[i][j] = 0.0f;

  for (int kc = 0; kc < 128; kc += 32) {
#pragma unroll
    for (int i = tid; i < 32 * BN / 4; i += 256) {
      reinterpret_cast<float4*>(&ws[0][0])[i] =
          reinterpret_cast<const float4*>(W + (size_t)kc * BN)[i];
    }
#pragma unroll
    for (int i = tid; i < 1024; i += 256) {
      int r = i >> 3, j = i & 7;
      int row = rowBase + r;
      float4 v = make_float4(0.f, 0.f, 0.f, 0.f);
      if (row < M)
        v = *reinterpret_cast<const float4*>(A + (size_t)row * 128 + kc + 4 * j);
      xs[4 * j + 0][r] = v.x;
      xs[4 * j + 1][r] = v.y;
      xs[4 * j + 2][r] = v.z;
      xs[4 * j + 3][r] = v.w;
    }
    __syncthreads();
#pragma unroll
    for (int k = 0; k < 32; k++) {
      float4 xa = *reinterpret_cast<const float4*>(&xs[k][ry]);
      float4 xb = *reinterpret_cast<const float4*>(&xs[k][ry + 4]);
      float xv[8] = {xa.x, xa.y, xa.z, xa.w, xb.x, xb.y, xb.z, xb.w};
      float wv[TN];
      float4 wa = *reinterpret_cast<const float4*>(&ws[k][cx]);
      wv[0] = wa.x; wv[1] = wa.y; wv[2] = wa.z; wv[3] = wa.w;
      if constexpr (TN == 8) {
        float4 wb = *reinterpret_cast<const float4*>(&ws[k][cx + 4]);
        wv[4] = wb.x; wv[5] = wb.y; wv[6] = wb.z; wv[7] = wb.w;
      }
#pragma unroll
      for (int i = 0; i < 8; i++)
#pragma unroll
        for (int j = 0; j < TN; j++) acc[i][j] += xv[i] * wv[j];
    }
    __syncthreads();
  }

#pragma unroll
  for (int i = 0; i < 8; i++) {
    int row = rowBase + ry + i;
    if (row < M) {
      float rs = ROWSCALE ? rowscale[row] : 1.0f;
      float* cp = C + (size_t)row * BN + cx;
#pragma unroll
      for (int j0 = 0; j0 < TN; j0 += 4) {
        float4 o = make_float4(acc[i][j0 + 0], acc[i][j0 + 1], acc[i][j0 + 2],
                               acc[i][j0 + 3]);
        if constexpr (BIASRELU) {
          float4 bv = *reinterpret_cast<const float4*>(&bias[cx + j0]);
          o.x = fmaxf(o.x + bv.x, 0.f);
          o.y = fmaxf(o.y + bv.y, 0.f);
          o.z = fmaxf(o.z + bv.z, 0.f);
          o.w = fmaxf(o.w + bv.w, 0.f);
        }
        if constexpr (ROWSCALE) {
          o.x *= rs; o.y *= rs; o.z *= rs; o.w *= rs;
        }
        *reinterpret_cast<float4*>(cp + j0) = o;
      }
    }
  }
}

extern "C" void kernel_launch(void* const* d_in, const int* in_sizes, int n_in,
                              void* d_out, int out_size, void* d_ws, size_t ws_size,
                              hipStream_t stream) {
  const float* x  = (const float*)d_in[0];
  const int*   ei = (const int*)d_in[1];  // [2, NE] row-major
  const int* rows = ei;
  const int* cols = ei + NE;
  const float* W1 = (const float*)d_in[3];
  const float* b1 = (const float*)d_in[4];
  const float* W2 = (const float*)d_in[5];
  const float* b2 = (const float*)d_in[6];
  float* out = (float*)d_out;

  // ---- workspace carve (~112.2 MB) ----
  char* base = (char*)d_ws;
  constexpr size_t MB = 1 << 20;
  int*   deg      = (int*)(base + 0 * MB);          // 400 KB
  int*   rowptr   = (int*)(base + 1 * MB);          // 400 KB (becomes end-ptrs)
  float* dinv     = (float*)(base + 2 * MB);        // 400 KB
  int*   blockSum = (int*)(base + 3 * MB);          // 512 B
  int*   blockOff = (int*)(base + 3 * MB + 4096);   // 512 B
  int*   srcIdx   = (int*)(base + 4 * MB);          // 6.4 MB
  float* bufA     = (float*)(base + 11 * MB);       // 51.2 MB: y, later h1
  float* bufB     = (float*)(base + 63 * MB);       // 51.2 MB: aggX, later z
  float* y = bufA, *aggx = bufB, *h1 = bufA, *z = bufB;

  constexpr int SCAN_BLOCKS = (NN + 1023) / 1024;  // 98

  hipMemsetAsync(deg, 0, NN * sizeof(int), stream);
  k_deg<<<(NE + 255) / 256, 256, 0, stream>>>(cols, deg);
  k_scanA<<<SCAN_BLOCKS, 256, 0, stream>>>(deg, rowptr, blockSum);
  k_scanB<<<1, 128, 0, stream>>>(blockSum, blockOff, SCAN_BLOCKS);
  k_scanC<<<(NN + 255) / 256, 256, 0, stream>>>(rowptr, blockOff, deg, dinv);
  k_fill<<<(NE + 255) / 256, 256, 0, stream>>>(rows, cols, rowptr, srcIdx);
  k_y<<<(NN * 32 + 255) / 256, 256, 0, stream>>>((const float4*)x, dinv, (float4*)y);
  k_gath1<<<(NN + 3) / 4, 256, 0, stream>>>((const float2*)y, rowptr, deg, srcIdx,
                                            dinv, (float2*)aggx);
  k_gemm<128, true, false><<<(NN + 127) / 128, 256, 0, stream>>>(aggx, W1, b1,
                                                                 nullptr, h1, NN);
  k_gemm<64, false, true><<<(NN + 127) / 128, 256, 0, stream>>>(h1, W2, nullptr,
                                                                dinv, z, NN);
  k_gath2<<<(NN + 3) / 4, 256, 0, stream>>>(z, rowptr, deg, srcIdx, dinv, b2, out);
}

// Round 3
// 505.496 us; speedup vs baseline: 8.5408x; 1.2727x over previous
//
#include <hip/hip_runtime.h>
#include <hip/hip_fp16.h>

// GCN 2-layer, CSR-gather formulation, fp16 storage / fp32 math.
// Agg(X@W) == Agg(X)@W. norm = dinv[r]*dinv[c] factored:
//   y = half(x * dinv)
//   aggX[c] = half( dinv[c] * (y[c] + sum_{r in in(c)} y[r]) )
//   h1 = half( relu(aggX @ W1 + b1) )
//   z  = half( (h1 @ W2) * dinv )
//   out[c] = fp32( dinv[c] * (z[c] + sum z[r]) + b2 )

constexpr int NN = 100000;   // nodes
constexpr int NE = 1600000;  // edges

// ---------------- degree histogram (int atomics, L2-resident) ----------------
__global__ __launch_bounds__(256) void k_deg(const int* __restrict__ cols,
                                             int* __restrict__ deg) {
  int e = blockIdx.x * 256 + threadIdx.x;
  if (e < NE) atomicAdd(&deg[cols[e]], 1);
}

// ---------------- exclusive scan of deg -> rowptr (3 kernels) ----------------
__global__ __launch_bounds__(256) void k_scanA(const int* __restrict__ deg,
                                               int* __restrict__ rowptr,
                                               int* __restrict__ blockSum) {
  __shared__ int s[256];
  int t = threadIdx.x, b = blockIdx.x;
  int base = b * 1024 + t * 4;
  int d0 = (base + 0 < NN) ? deg[base + 0] : 0;
  int d1 = (base + 1 < NN) ? deg[base + 1] : 0;
  int d2 = (base + 2 < NN) ? deg[base + 2] : 0;
  int d3 = (base + 3 < NN) ? deg[base + 3] : 0;
  int tsum = d0 + d1 + d2 + d3;
  s[t] = tsum;
  __syncthreads();
  for (int off = 1; off < 256; off <<= 1) {
    int tmp = (t >= off) ? s[t - off] : 0;
    __syncthreads();
    s[t] += tmp;
    __syncthreads();
  }
  int ex = s[t] - tsum;
  if (base + 0 < NN) rowptr[base + 0] = ex;
  if (base + 1 < NN) rowptr[base + 1] = ex + d0;
  if (base + 2 < NN) rowptr[base + 2] = ex + d0 + d1;
  if (base + 3 < NN) rowptr[base + 3] = ex + d0 + d1 + d2;
  if (t == 255) blockSum[b] = ex + tsum;
}

__global__ __launch_bounds__(128) void k_scanB(int* __restrict__ blockSum,
                                               int* __restrict__ blockOff,
                                               int nblocks) {
  __shared__ int s[128];
  int t = threadIdx.x;
  int v = (t < nblocks) ? blockSum[t] : 0;
  s[t] = v;
  __syncthreads();
  for (int off = 1; off < 128; off <<= 1) {
    int tmp = (t >= off) ? s[t - off] : 0;
    __syncthreads();
    s[t] += tmp;
    __syncthreads();
  }
  if (t < nblocks) blockOff[t] = s[t] - v;
}

__global__ __launch_bounds__(256) void k_scanC(int* __restrict__ rowptr,
                                               const int* __restrict__ blockOff,
                                               const int* __restrict__ deg,
                                               float* __restrict__ dinv) {
  int i = blockIdx.x * 256 + threadIdx.x;
  if (i < NN) {
    rowptr[i] += blockOff[i >> 10];
    dinv[i] = rsqrtf((float)deg[i] + 1.0f);
  }
}

// ---------------- CSR fill: rowptr becomes END pointers ----------------
__global__ __launch_bounds__(256) void k_fill(const int* __restrict__ rows,
                                              const int* __restrict__ cols,
                                              int* __restrict__ rowptr,
                                              int* __restrict__ srcIdx) {
  int e = blockIdx.x * 256 + threadIdx.x;
  if (e < NE) {
    int c = cols[e];
    int pos = atomicAdd(&rowptr[c], 1);
    srcIdx[pos] = rows[e];
  }
}

// ---------------- y = half(x * dinv) ----------------
__global__ __launch_bounds__(256) void k_y(const float4* __restrict__ x4,
                                           const float* __restrict__ dinv,
                                           float2* __restrict__ y8) {
  int gid = blockIdx.x * 256 + threadIdx.x;  // NN*32 float4 units
  if (gid >= NN * 32) return;
  float s = dinv[gid >> 5];
  float4 v = x4[gid];
  union { __half2 h[2]; float2 f; } u;
  u.h[0] = __floats2half2_rn(v.x * s, v.y * s);
  u.h[1] = __floats2half2_rn(v.z * s, v.w * s);
  y8[gid] = u.f;
}

// ---------------- gather-aggregate, width 128 half (wave per node) -----------
__global__ __launch_bounds__(256) void k_gath1(const __half2* __restrict__ y2,
                                               const int* __restrict__ rowptr_end,
                                               const int* __restrict__ deg,
                                               const int* __restrict__ srcIdx,
                                               const float* __restrict__ dinv,
                                               __half2* __restrict__ agg) {
  int node = blockIdx.x * 4 + (threadIdx.x >> 6);
  int lane = threadIdx.x & 63;
  if (node >= NN) return;
  int d = deg[node];
  int p = rowptr_end[node] - d;  // start
  size_t rb = (size_t)node * 64 + lane;
  float2 acc = __half22float2(y2[rb]);  // self-loop term
  for (int base = 0; base < d; base += 64) {
    int cnt = min(64, d - base);
    int my = (lane < cnt) ? srcIdx[p + base + lane] : 0;
    int k = 0;
    for (; k + 2 <= cnt; k += 2) {
      int s0 = __shfl(my, k);
      int s1 = __shfl(my, k + 1);
      float2 v0 = __half22float2(y2[(size_t)s0 * 64 + lane]);
      float2 v1 = __half22float2(y2[(size_t)s1 * 64 + lane]);
      acc.x += v0.x + v1.x;
      acc.y += v0.y + v1.y;
    }
    if (k < cnt) {
      int s0 = __shfl(my, k);
      float2 v0 = __half22float2(y2[(size_t)s0 * 64 + lane]);
      acc.x += v0.x;
      acc.y += v0.y;
    }
  }
  float sc = dinv[node];
  agg[rb] = __floats2half2_rn(acc.x * sc, acc.y * sc);
}

// ---------------- gather-aggregate, width 64 half (half-wave per node) -------
__global__ __launch_bounds__(256) void k_gath2(const __half2* __restrict__ z2,
                                               const int* __restrict__ rowptr_end,
                                               const int* __restrict__ deg,
                                               const int* __restrict__ srcIdx,
                                               const float* __restrict__ dinv,
                                               const float* __restrict__ b2,
                                               float2* __restrict__ out2) {
  int node = blockIdx.x * 8 + (threadIdx.x >> 5);
  int lane = threadIdx.x & 31;
  if (node >= NN) return;
  int d = deg[node];
  int p = rowptr_end[node] - d;
  float2 acc = __half22float2(z2[(size_t)node * 32 + lane]);
  for (int base = 0; base < d; base += 32) {
    int cnt = min(32, d - base);
    int my = (lane < cnt) ? srcIdx[p + base + lane] : 0;
    int k = 0;
    for (; k + 2 <= cnt; k += 2) {
      int s0 = __shfl(my, k, 32);
      int s1 = __shfl(my, k + 1, 32);
      float2 v0 = __half22float2(z2[(size_t)s0 * 32 + lane]);
      float2 v1 = __half22float2(z2[(size_t)s1 * 32 + lane]);
      acc.x += v0.x + v1.x;
      acc.y += v0.y + v1.y;
    }
    if (k < cnt) {
      int s0 = __shfl(my, k, 32);
      float2 v0 = __half22float2(z2[(size_t)s0 * 32 + lane]);
      acc.x += v0.x;
      acc.y += v0.y;
    }
  }
  float s = dinv[node];
  float2 bv = reinterpret_cast<const float2*>(b2)[lane];
  out2[(size_t)node * 32 + lane] = make_float2(acc.x * s + bv.x, acc.y * s + bv.y);
}

// ---- GEMM: C[M,BN] = A[M,128] @ W[128,BN], A/C half storage, fp32 math ------
template <int BN, bool BIASRELU, bool ROWSCALE>
__global__ __launch_bounds__(256) void k_gemm(const __half2* __restrict__ A2,
                                              const float* __restrict__ W,
                                              const float* __restrict__ bias,
                                              const float* __restrict__ rowscale,
                                              __half* __restrict__ C, int M) {
  constexpr int TN = BN / 16;  // 8 or 4
  __shared__ __align__(16) float xs[32][132];
  __shared__ __align__(16) float ws[32][BN];
  const int tid = threadIdx.x;
  const int tx = tid & 15, ty = tid >> 4;
  const int ry = ty * 8, cx = tx * TN;
  const int rowBase = blockIdx.x * 128;

  float acc[8][TN];
#pragma unroll
  for (int i = 0; i < 8; i++)
#pragma unroll
    for (int j = 0; j < TN; j++) acc[i][j] = 0.0f;

  for (int kc = 0; kc < 128; kc += 32) {
#pragma unroll
    for (int i = tid; i < 32 * BN / 4; i += 256) {
      reinterpret_cast<float4*>(&ws[0][0])[i] =
          reinterpret_cast<const float4*>(W + (size_t)kc * BN)[i];
    }
    // stage A chunk transposed: xs[k][r]; A rows are 64 half2
#pragma unroll
    for (int i = tid; i < 1024; i += 256) {
      int r = i >> 3, j = i & 7;
      int row = rowBase + r;
      float4 v = make_float4(0.f, 0.f, 0.f, 0.f);
      if (row < M) {
        union { float2 f; __half2 h[2]; } u;
        u.f = *reinterpret_cast<const float2*>(A2 + (size_t)row * 64 + (kc >> 1) + 2 * j);
        float2 f0 = __half22float2(u.h[0]);
        float2 f1 = __half22float2(u.h[1]);
        v = make_float4(f0.x, f0.y, f1.x, f1.y);
      }
      xs[4 * j + 0][r] = v.x;
      xs[4 * j + 1][r] = v.y;
      xs[4 * j + 2][r] = v.z;
      xs[4 * j + 3][r] = v.w;
    }
    __syncthreads();
#pragma unroll
    for (int k = 0; k < 32; k++) {
      float4 xa = *reinterpret_cast<const float4*>(&xs[k][ry]);
      float4 xb = *reinterpret_cast<const float4*>(&xs[k][ry + 4]);
      float xv[8] = {xa.x, xa.y, xa.z, xa.w, xb.x, xb.y, xb.z, xb.w};
      float wv[TN];
      float4 wa = *reinterpret_cast<const float4*>(&ws[k][cx]);
      wv[0] = wa.x; wv[1] = wa.y; wv[2] = wa.z; wv[3] = wa.w;
      if constexpr (TN == 8) {
        float4 wb = *reinterpret_cast<const float4*>(&ws[k][cx + 4]);
        wv[4] = wb.x; wv[5] = wb.y; wv[6] = wb.z; wv[7] = wb.w;
      }
#pragma unroll
      for (int i = 0; i < 8; i++)
#pragma unroll
        for (int j = 0; j < TN; j++) acc[i][j] += xv[i] * wv[j];
    }
    __syncthreads();
  }

#pragma unroll
  for (int i = 0; i < 8; i++) {
    int row = rowBase + ry + i;
    if (row < M) {
      float rs = ROWSCALE ? rowscale[row] : 1.0f;
      float vals[TN];
#pragma unroll
      for (int j = 0; j < TN; j++) {
        float v = acc[i][j];
        if constexpr (BIASRELU) v = fmaxf(v + bias[cx + j], 0.f);
        if constexpr (ROWSCALE) v *= rs;
        vals[j] = v;
      }
      __half* cp = C + (size_t)row * BN + cx;
      if constexpr (TN == 8) {
        union { __half2 h[4]; float4 f; } u;
        u.h[0] = __floats2half2_rn(vals[0], vals[1]);
        u.h[1] = __floats2half2_rn(vals[2], vals[3]);
        u.h[2] = __floats2half2_rn(vals[4], vals[5]);
        u.h[3] = __floats2half2_rn(vals[6], vals[7]);
        *reinterpret_cast<float4*>(cp) = u.f;
      } else {
        union { __half2 h[2]; float2 f; } u;
        u.h[0] = __floats2half2_rn(vals[0], vals[1]);
        u.h[1] = __floats2half2_rn(vals[2], vals[3]);
        *reinterpret_cast<float2*>(cp) = u.f;
      }
    }
  }
}

extern "C" void kernel_launch(void* const* d_in, const int* in_sizes, int n_in,
                              void* d_out, int out_size, void* d_ws, size_t ws_size,
                              hipStream_t stream) {
  const float* x  = (const float*)d_in[0];
  const int*   ei = (const int*)d_in[1];  // [2, NE] row-major
  const int* rows = ei;
  const int* cols = ei + NE;
  const float* W1 = (const float*)d_in[3];
  const float* b1 = (const float*)d_in[4];
  const float* W2 = (const float*)d_in[5];
  const float* b2 = (const float*)d_in[6];
  float* out = (float*)d_out;

  // ---- workspace carve (~89 MB) ----
  char* base = (char*)d_ws;
  constexpr size_t MB = 1 << 20;
  int*     deg      = (int*)(base + 0 * MB);
  int*     rowptr   = (int*)(base + 1 * MB);
  float*   dinv     = (float*)(base + 2 * MB);
  int*     blockSum = (int*)(base + 3 * MB);
  int*     blockOff = (int*)(base + 3 * MB + 4096);
  int*     srcIdx   = (int*)(base + 4 * MB);             // 6.4 MB
  __half2* y        = (__half2*)(base + 11 * MB);        // 25.6 MB (reused for z)
  __half*  aggx     = (__half*)(base + 37 * MB);         // 25.6 MB
  __half*  h1       = (__half*)(base + 63 * MB);         // 25.6 MB
  __half2* z        = (__half2*)(base + 11 * MB);        // 12.8 MB (y dead)

  constexpr int SCAN_BLOCKS = (NN + 1023) / 1024;  // 98

  hipMemsetAsync(deg, 0, NN * sizeof(int), stream);
  k_deg<<<(NE + 255) / 256, 256, 0, stream>>>(cols, deg);
  k_scanA<<<SCAN_BLOCKS, 256, 0, stream>>>(deg, rowptr, blockSum);
  k_scanB<<<1, 128, 0, stream>>>(blockSum, blockOff, SCAN_BLOCKS);
  k_scanC<<<(NN + 255) / 256, 256, 0, stream>>>(rowptr, blockOff, deg, dinv);
  k_fill<<<(NE + 255) / 256, 256, 0, stream>>>(rows, cols, rowptr, srcIdx);
  k_y<<<(NN * 32 + 255) / 256, 256, 0, stream>>>((const float4*)x, dinv, (float2*)y);
  k_gath1<<<(NN + 3) / 4, 256, 0, stream>>>(y, rowptr, deg, srcIdx, dinv,
                                            (__half2*)aggx);
  k_gemm<128, true, false><<<(NN + 127) / 128, 256, 0, stream>>>(
      (const __half2*)aggx, W1, b1, nullptr, h1, NN);
  k_gemm<64, false, true><<<(NN + 127) / 128, 256, 0, stream>>>(
      (const __half2*)h1, W2, nullptr, dinv, (__half*)z, NN);
  k_gath2<<<(NN + 7) / 8, 256, 0, stream>>>(z, rowptr, deg, srcIdx, dinv, b2,
                                            (float2*)out);
}